// Round 9
// baseline (692.085 us; speedup 1.0000x reference)
//
#include <hip/hip_runtime.h>
#include <hip/hip_bf16.h>

#define NN 10000
#define NE 100000

typedef __bf16   bf16x8 __attribute__((ext_vector_type(8)));
typedef _Float16 f16x8  __attribute__((ext_vector_type(8)));
typedef _Float16 f16x2  __attribute__((ext_vector_type(2)));
typedef float    f32x4  __attribute__((ext_vector_type(4)));

__device__ __forceinline__ f32x4 relu4(f32x4 a) {
    a.x = fmaxf(a.x, 0.f); a.y = fmaxf(a.y, 0.f);
    a.z = fmaxf(a.z, 0.f); a.w = fmaxf(a.w, 0.f);
    return a;
}

__device__ __forceinline__ float fdot2h(f16x2 a, f16x2 b, float c) {
#if defined(__has_builtin)
#if __has_builtin(__builtin_amdgcn_fdot2)
    return __builtin_amdgcn_fdot2(a, b, c, false);
#else
    return c + (float)a.x * (float)b.x + (float)a.y * (float)b.y;
#endif
#else
    return c + (float)a.x * (float)b.x + (float)a.y * (float)b.y;
#endif
}

// ---------------- one-time kernels ----------------

__global__ void k_deg(const int* __restrict__ eidx, int* __restrict__ deg_r,
                      int* __restrict__ deg_c) {
    int e = blockIdx.x * blockDim.x + threadIdx.x;
    if (e < NE) {
        atomicAdd(&deg_r[eidx[e]], 1);
        atomicAdd(&deg_c[eidx[NE + e]], 1);
    }
}

// blockIdx.x==0: row scan; ==1: col scan. Exclusive prefix -> ptr[NN+1], cursor.
__global__ void k_scan(const int* __restrict__ degA, int* __restrict__ ptrA, int* __restrict__ curA,
                       const int* __restrict__ degB, int* __restrict__ ptrB, int* __restrict__ curB) {
    const int* deg = blockIdx.x ? degB : degA;
    int* ptr = blockIdx.x ? ptrB : ptrA;
    int* cur = blockIdx.x ? curB : curA;
    __shared__ int ssum[256];
    const int tid = threadIdx.x;
    const int CH = 40;
    const int base = tid * CH;
    int s = 0;
    for (int i = 0; i < CH; ++i) { int n = base + i; if (n < NN) s += deg[n]; }
    ssum[tid] = s;
    __syncthreads();
    for (int off = 1; off < 256; off <<= 1) {
        int t = (tid >= off) ? ssum[tid - off] : 0;
        __syncthreads();
        ssum[tid] += t;
        __syncthreads();
    }
    int run = ssum[tid] - s;
    for (int i = 0; i < CH; ++i) {
        int n = base + i;
        if (n < NN) { ptr[n] = run; cur[n] = run; run += deg[n]; }
    }
    if (tid == 255) ptr[NN] = ssum[255];
}

__global__ void k_fill(const int* __restrict__ eidx, int* __restrict__ cur_r,
                       int* __restrict__ cur_c, int* __restrict__ ebyrow,
                       int* __restrict__ ebycol) {
    int e = blockIdx.x * blockDim.x + threadIdx.x;
    if (e < NE) {
        int sr = atomicAdd(&cur_r[eidx[e]], 1);
        ebyrow[sr] = e;
        int sc = atomicAdd(&cur_c[eidx[NE + e]], 1);
        ebycol[sc] = e;
    }
}

__global__ void k_init(const float* __restrict__ x, const float* __restrict__ fc1w,
                       const float* __restrict__ fc1b, const float* __restrict__ cinit,
                       const int* __restrict__ deg,
                       float* __restrict__ h, float* __restrict__ coord,
                       float* __restrict__ deg_inv) {
    int n = blockIdx.x * blockDim.x + threadIdx.x;
    if (n >= NN) return;
    float x0 = x[n*3+0], x1 = x[n*3+1], x2 = x[n*3+2];
    #pragma unroll
    for (int j = 0; j < 32; j += 4) {
        f32x4 a = *(const f32x4*)(fc1b + j);
        a += x0 * (*(const f32x4*)(fc1w + 0*32 + j));
        a += x1 * (*(const f32x4*)(fc1w + 1*32 + j));
        a += x2 * (*(const f32x4*)(fc1w + 2*32 + j));
        *(f32x4*)(h + n*32 + j) = a;   // no relu on fc1 (matches reference)
    }
    coord[n*3+0] = cinit[n*3+0];
    coord[n*3+1] = cinit[n*3+1];
    coord[n*3+2] = cinit[n*3+2];
    int d = deg[n];
    deg_inv[n] = 1.0f / (float)(d > 1 ? d : 1);
}

// Bsw: fp16 B-frag layout of W3''[j][c], 4352 cols: c = g*256 + i*8 + u,
// kidx = g*8+u (g=0..16). kidx<128 -> W3 row; 128 -> b3; >=129 -> 0.
// Also w2sw (bf16 B-frag of ker_w2, for k_edge12).
__global__ void k_wsw(const float* __restrict__ w3, const float* __restrict__ b3,
                      _Float16* __restrict__ Bsw,
                      const float* __restrict__ w2, __bf16* __restrict__ w2sw) {
    int t = blockIdx.x * blockDim.x + threadIdx.x;
    if (t < 139264) {                        // 272 nt-tiles x 512
        int jj = t & 7;
        int L  = (t >> 3) & 63;
        int nt = t >> 9;                     // 0..271
        int j  = (L >> 4)*8 + jj;            // K index 0..31
        int c  = nt*16 + (L & 15);           // col 0..4351
        int g   = c >> 8;
        int rem = c & 255;
        int io  = rem >> 3;
        int u   = rem & 7;
        int kidx = g*8 + u;                  // 0..135
        float v = 0.0f;
        if (kidx < 128)       v = w3[kidx*1024 + io*32 + j];
        else if (kidx == 128) v = b3[io*32 + j];
        Bsw[t] = (_Float16)v;
    } else if (t < 139264 + 8192) {
        int u = t - 139264;
        int jj = u & 7;
        int L  = (u >> 3) & 63;
        int ks = (u >> 9) & 1;
        int nt = u >> 10;
        int c1 = ks*32 + (L >> 4)*8 + jj;
        int c2 = nt*16 + (L & 15);
        w2sw[u] = (__bf16)w2[c1*128 + c2];
    }
}

// ---------------- per-layer kernels ----------------

// Fused edge MLP: coord_diff/radial -> layer1 (per-lane, 64ch in regs) ->
// XOR-swizzled per-wave LDS tile -> A-frags -> layer2 MFMA -> kbf [E,128] fp16.
__global__ __launch_bounds__(256, 2)
void k_edge12(const float* __restrict__ coord, const int* __restrict__ eidx,
              const float* __restrict__ eattr,
              const float* __restrict__ w1, const float* __restrict__ b1,
              const __bf16* __restrict__ w2sw, const float* __restrict__ b2,
              float* __restrict__ cd4, _Float16* __restrict__ kbf) {
    __shared__ __bf16 ktile[4][4096];
    const int tid = threadIdx.x;
    const int wave = tid >> 6, lane = tid & 63;
    const int q = lane >> 4, t = lane & 15;
    const int e = blockIdx.x * 256 + tid;
    const int ec = e < NE ? e : NE - 1;
    const int wbase = blockIdx.x * 256 + wave * 64;
    __bf16* kt = ktile[wave];

    int r = eidx[ec], c = eidx[NE + ec];
    float dx = coord[r*3+0] - coord[c*3+0];
    float dy = coord[r*3+1] - coord[c*3+1];
    float dz = coord[r*3+2] - coord[c*3+2];
    float rad = dx*dx + dy*dy + dz*dz;
    if (e < NE) {
        f32x4 cdv = {dx, dy, dz, rad};
        *(f32x4*)(cd4 + (size_t)e*4) = cdv;
    }
    float kin[7];
    #pragma unroll
    for (int a = 0; a < 6; ++a) kin[a] = eattr[(size_t)ec*6 + a];
    kin[6] = rad;

    f32x4 acc1[16];
    #pragma unroll
    for (int g = 0; g < 16; ++g) acc1[g] = *(const f32x4*)(b1 + g*4);
    #pragma unroll
    for (int t7 = 0; t7 < 7; ++t7) {
        float kv = kin[t7];
        #pragma unroll
        for (int g = 0; g < 16; ++g)
            acc1[g] += kv * (*(const f32x4*)(w1 + t7*64 + g*4));
    }
    #pragma unroll
    for (int cc = 0; cc < 8; ++cc) {
        f32x4 a0 = relu4(acc1[cc*2]), a1 = relu4(acc1[cc*2+1]);
        bf16x8 pk = {(__bf16)a0.x, (__bf16)a0.y, (__bf16)a0.z, (__bf16)a0.w,
                     (__bf16)a1.x, (__bf16)a1.y, (__bf16)a1.z, (__bf16)a1.w};
        *(bf16x8*)(kt + lane*64 + ((cc ^ (lane & 7)) * 8)) = pk;
    }
    __syncthreads();

    bf16x8 af[4][2];
    #pragma unroll
    for (int mt = 0; mt < 4; ++mt) {
        int ep = mt*16 + t;
        #pragma unroll
        for (int ks = 0; ks < 2; ++ks)
            af[mt][ks] = *(const bf16x8*)(kt + ep*64 + (((ks*4 + q) ^ (ep & 7)) * 8));
    }

    for (int nt = 0; nt < 8; ++nt) {
        f32x4 a2[4];
        #pragma unroll
        for (int mt = 0; mt < 4; ++mt) a2[mt] = (f32x4){0.f, 0.f, 0.f, 0.f};
        #pragma unroll
        for (int ks = 0; ks < 2; ++ks) {
            bf16x8 bf_ = *(const bf16x8*)(w2sw + ((nt*2 + ks)*64 + lane) * 8);
            #pragma unroll
            for (int mt = 0; mt < 4; ++mt)
                a2[mt] = __builtin_amdgcn_mfma_f32_16x16x32_bf16(af[mt][ks], bf_, a2[mt], 0, 0, 0);
        }
        float bias = b2[nt*16 + t];
        #pragma unroll
        for (int mt = 0; mt < 4; ++mt) {
            #pragma unroll
            for (int rr = 0; rr < 4; ++rr) {
                int e2 = wbase + mt*16 + q*4 + rr;
                if (e2 < NE)
                    kbf[(size_t)e2*128 + nt*16 + t] = (_Float16)fmaxf(a2[mt][rr] + bias, 0.f);
            }
        }
    }
}

// Node GEMM: P[n][c] = sum_j W3''[j][c] * h[n][j], c-layout [g][i][u], row 4352.
// MFMA f16, 1 wave over 64 nodes, grid.y=34 x 4 pidx (32-col pairs) per wave.
__global__ __launch_bounds__(64, 4)
void k_pmat(const float* __restrict__ h, const _Float16* __restrict__ Bsw,
            _Float16* __restrict__ P, int n0, int n1) {
    __shared__ _Float16 tile[64 * 40];
    const int lane = threadIdx.x;
    const int q = lane >> 4, t = lane & 15;
    const int nbase = n0 + blockIdx.x * 64;

    f16x8 af[4];
    #pragma unroll
    for (int mt = 0; mt < 4; ++mt) {
        int node = nbase + mt*16 + t;
        node = node < NN ? node : NN - 1;
        const float* hp = h + (size_t)node*32 + q*8;
        f32x4 h0 = *(const f32x4*)(hp);
        f32x4 h1 = *(const f32x4*)(hp + 4);
        af[mt] = (f16x8){(_Float16)h0.x, (_Float16)h0.y, (_Float16)h0.z, (_Float16)h0.w,
                         (_Float16)h1.x, (_Float16)h1.y, (_Float16)h1.z, (_Float16)h1.w};
    }

    const int node_s = nbase + lane;
    const bool do_store = (node_s < n1) && (node_s < NN);
    _Float16* prow = P + (size_t)(node_s - n0) * 4352;

    for (int w = 0; w < 4; ++w) {
        int pidx = blockIdx.y * 4 + w;        // 0..135
        #pragma unroll
        for (int hf = 0; hf < 2; ++hf) {
            int nt = pidx*2 + hf;             // 0..271
            f16x8 bf_ = *(const f16x8*)(Bsw + nt*512 + lane*8);
            #pragma unroll
            for (int mt = 0; mt < 4; ++mt) {
                f32x4 acc = (f32x4){0.f, 0.f, 0.f, 0.f};
                acc = __builtin_amdgcn_mfma_f32_16x16x32_f16(af[mt], bf_, acc, 0, 0, 0);
                #pragma unroll
                for (int rr = 0; rr < 4; ++rr)
                    tile[(mt*16 + q*4 + rr)*40 + hf*16 + t] = (_Float16)acc[rr];
            }
        }
        if (do_store) {
            const f16x8* tr = (const f16x8*)(tile + lane*40);
            f16x8 v0 = tr[0], v1 = tr[1], v2 = tr[2], v3 = tr[3];
            _Float16* dst = prow + pidx*32;
            *(f16x8*)(dst)      = v0;
            *(f16x8*)(dst + 8)  = v1;
            *(f16x8*)(dst + 16) = v2;
            *(f16x8*)(dst + 24) = v3;
        }
    }
}

// Per-NODE message kernel: one wave per node. P[n] staged to LDS once (8.7 KB),
// edges processed 2 at a time: lane (hf,i) computes m[e_hf][i] via 16x
// (ds_read_b128 + 4 dot2). phi fused via per-wave LDS exchange + shfl reduce.
// No __syncthreads (all LDS traffic is wave-private).
__global__ __launch_bounds__(256, 4)
void k_msg(const _Float16* __restrict__ kbf, const _Float16* __restrict__ P,
           const int* __restrict__ colptr, const int* __restrict__ ebycol,
           const float* __restrict__ cm_w1, const float* __restrict__ cm_b1,
           const float* __restrict__ cm_w2,
           float* __restrict__ m_t, float* __restrict__ phiv, int n0, int n1) {
    __shared__ _Float16 ldsP[4][4352];
    __shared__ float    mex[4][64];
    const int wave = threadIdx.x >> 6, lane = threadIdx.x & 63;
    const int hf = lane >> 5, i = lane & 31;
    const int n = n0 + blockIdx.x * 4 + wave;
    if (n >= n1) return;

    // stage P[n] into this wave's LDS region
    _Float16* lp = ldsP[wave];
    {
        const f16x8* src = (const f16x8*)(P + (size_t)(n - n0) * 4352);
        f16x8* dst = (f16x8*)lp;
        #pragma unroll
        for (int r = 0; r < 9; ++r) {
            int idx = r*64 + lane;
            if (idx < 544) dst[idx] = src[idx];
        }
    }

    const int st = colptr[n], en = colptr[n+1];
    const float w1col = 0.f; (void)w1col;
    for (int p = st; p < en; p += 2) {
        const int pe = p + hf;
        const bool valid = pe < en;
        const int e = ebycol[valid ? pe : p];

        const f16x8* kk8 = (const f16x8*)(kbf + (size_t)e * 128);
        float acc = 0.f;
        #pragma unroll
        for (int g = 0; g < 16; ++g) {
            f16x8 kv = kk8[g];
            f16x8 pv = *(const f16x8*)(lp + g*256 + i*8);
            #pragma unroll
            for (int uu = 0; uu < 4; ++uu) {
                f16x2 ka = {kv[2*uu], kv[2*uu+1]};
                f16x2 pa = {pv[2*uu], pv[2*uu+1]};
                acc = fdot2h(ka, pa, acc);
            }
        }
        acc += (float)lp[16*256 + i*8];     // bias row (kidx=128, kk==1)

        if (valid) m_t[(size_t)e*32 + i] = acc;

        // phi: exchange m across the 32-lane half, then per-lane output o=i
        mex[wave][lane] = acc;
        const float* mrow = &mex[wave][hf*32];
        float ao = cm_b1[i];
        #pragma unroll 8
        for (int ii = 0; ii < 32; ++ii)
            ao += mrow[ii] * cm_w1[ii*32 + i];
        ao = fmaxf(ao, 0.f);
        float contrib = ao * cm_w2[i];
        #pragma unroll
        for (int mm = 1; mm <= 16; mm <<= 1)
            contrib += __shfl_xor(contrib, mm, 64);
        if (i == 0 && valid) phiv[e] = contrib;
    }
}

// CSR gather: 8 threads per node.
__global__ __launch_bounds__(256, 4)
void k_gather(const int* __restrict__ rowptr, const int* __restrict__ ebyrow,
              const float* __restrict__ m_t, const float* __restrict__ phiv,
              const float* __restrict__ cd4, const float* __restrict__ deg_inv,
              float* __restrict__ coord, float* __restrict__ h) {
    int tid = blockIdx.x * blockDim.x + threadIdx.x;
    int n = tid >> 3, sub = tid & 7;
    if (n >= NN) return;
    int st = rowptr[n], en = rowptr[n+1];
    f32x4 am = {0.f, 0.f, 0.f, 0.f};
    float cx = 0.f, cy = 0.f, cz = 0.f;
    for (int p = st; p < en; ++p) {
        int e = ebyrow[p];
        am += *(const f32x4*)(m_t + (size_t)e*32 + sub*4);
        if (sub == 0) {
            f32x4 cd = *(const f32x4*)(cd4 + (size_t)e*4);
            float ph = phiv[e];
            cx += cd.x * ph; cy += cd.y * ph; cz += cd.z * ph;
        }
    }
    float di = deg_inv[n];
    f32x4 hv = *(const f32x4*)(h + (size_t)n*32 + sub*4);
    hv = relu4(hv + am * di);
    *(f32x4*)(h + (size_t)n*32 + sub*4) = hv;
    if (sub == 0) {
        coord[n*3+0] += cx * di;
        coord[n*3+1] += cy * di;
        coord[n*3+2] += cz * di;
    }
}

__global__ __launch_bounds__(256, 4)
void k_final(const float* __restrict__ h, const float* __restrict__ coord,
             const float* __restrict__ fw1, const float* __restrict__ fb1,
             const float* __restrict__ fw2, const float* __restrict__ fb2,
             float* __restrict__ out) {
    int n = blockIdx.x * blockDim.x + threadIdx.x;
    if (n >= NN) return;
    float hreg[32];
    #pragma unroll
    for (int i = 0; i < 32; ++i) hreg[i] = h[n*32 + i];
    float ov = fb2[0];
    for (int o = 0; o < 64; o += 4) {
        f32x4 a = *(const f32x4*)(fb1 + o);
        #pragma unroll
        for (int i = 0; i < 32; ++i)
            a += hreg[i] * (*(const f32x4*)(fw1 + i*64 + o));
        a = relu4(a);
        f32x4 w2 = *(const f32x4*)(fw2 + o);
        ov += a.x*w2.x + a.y*w2.y + a.z*w2.z + a.w*w2.w;
    }
    out[n] = ov;
    out[NN + n*3 + 0] = coord[n*3+0];
    out[NN + n*3 + 1] = coord[n*3+1];
    out[NN + n*3 + 2] = coord[n*3+2];
}

// ---------------- launch ----------------

extern "C" void kernel_launch(void* const* d_in, const int* in_sizes, int n_in,
                              void* d_out, int out_size, void* d_ws, size_t ws_size,
                              hipStream_t stream) {
    const float* x      = (const float*)d_in[0];
    const int*   eidx   = (const int*)  d_in[1];
    const float* eattr  = (const float*)d_in[2];
    const float* cinit  = (const float*)d_in[3];
    const float* fc1w   = (const float*)d_in[4];
    const float* fc1b   = (const float*)d_in[5];
    const float* kw1    = (const float*)d_in[6];
    const float* kb1    = (const float*)d_in[7];
    const float* kw2    = (const float*)d_in[8];
    const float* kb2    = (const float*)d_in[9];
    const float* kw3    = (const float*)d_in[10];
    const float* kb3    = (const float*)d_in[11];
    const float* cmw1   = (const float*)d_in[12];
    const float* cmb1   = (const float*)d_in[13];
    const float* cmw2   = (const float*)d_in[14];
    const float* f2w1   = (const float*)d_in[15];
    const float* f2b1   = (const float*)d_in[16];
    const float* f2w2   = (const float*)d_in[17];
    const float* f2b2   = (const float*)d_in[18];
    float* out = (float*)d_out;

    char* p = (char*)d_ws;
    auto carve = [&](size_t bytes) {
        void* r = (void*)p;
        p += (bytes + 255) & ~(size_t)255;
        return r;
    };
    float*     h        = (float*)    carve((size_t)NN * 32 * 4);
    float*     coord    = (float*)    carve((size_t)NN * 3 * 4);
    int*       degs     = (int*)      carve((size_t)2 * NN * 4);
    float*     deg_inv  = (float*)    carve((size_t)NN * 4);
    int*       rowptr   = (int*)      carve((size_t)(NN + 1) * 4);
    int*       colptr   = (int*)      carve((size_t)(NN + 1) * 4);
    int*       cur_r    = (int*)      carve((size_t)NN * 4);
    int*       cur_c    = (int*)      carve((size_t)NN * 4);
    int*       ebyrow   = (int*)      carve((size_t)NE * 4);
    int*       ebycol   = (int*)      carve((size_t)NE * 4);
    float*     cd4      = (float*)    carve((size_t)NE * 4 * 4);
    float*     m_t      = (float*)    carve((size_t)NE * 32 * 4);
    float*     phiv     = (float*)    carve((size_t)NE * 4);
    _Float16*  kbf      = (_Float16*) carve((size_t)NE * 128 * 2);
    _Float16*  Bsw      = (_Float16*) carve((size_t)139264 * 2);
    __bf16*    w2sw     = (__bf16*)   carve((size_t)8192 * 2);

    // P chunking: single chunk if workspace allows (branch on ws_size is
    // call-invariant -> graph-safe), else 2 chunks (round-8's proven footprint).
    size_t used = (size_t)(p - (char*)d_ws);
    size_t pfull = (size_t)NN * 4352 * 2 + 4096;
    int nc = (ws_size - used >= pfull) ? 1 : 2;
    int chN = (NN + nc - 1) / nc;
    _Float16* Pbuf = (_Float16*)carve((size_t)chN * 4352 * 2);
    int* deg_r = degs;
    int* deg_c = degs + NN;

    const int TB = 256;
    dim3 gE((NE + TB - 1) / TB), gN((NN + TB - 1) / TB), b(TB);
    dim3 gA((NN*8 + TB - 1) / TB);

    hipMemsetAsync(degs, 0, (size_t)2 * NN * 4, stream);
    k_deg <<<gE, b, 0, stream>>>(eidx, deg_r, deg_c);
    k_scan<<<2, b, 0, stream>>>(deg_r, rowptr, cur_r, deg_c, colptr, cur_c);
    k_fill<<<gE, b, 0, stream>>>(eidx, cur_r, cur_c, ebyrow, ebycol);
    k_init<<<gN, b, 0, stream>>>(x, fc1w, fc1b, cinit, deg_r, h, coord, deg_inv);
    k_wsw <<<576, b, 0, stream>>>(kw3, kb3, Bsw, kw2, w2sw);

    for (int d = 0; d < 3; ++d) {
        k_edge12<<<gE, b, 0, stream>>>(coord, eidx, eattr, kw1, kb1, w2sw, kb2, cd4, kbf);
        for (int ch = 0; ch < nc; ++ch) {
            int n0 = ch * chN;
            int n1 = (n0 + chN < NN) ? n0 + chN : NN;
            int cn = n1 - n0;
            dim3 gP((cn + 63) / 64, 34);
            dim3 gM((cn + 3) / 4);
            k_pmat<<<gP, dim3(64), 0, stream>>>(h, Bsw, Pbuf, n0, n1);
            k_msg <<<gM, b, 0, stream>>>(kbf, Pbuf, colptr, ebycol,
                                         cmw1, cmb1, cmw2, m_t, phiv, n0, n1);
        }
        k_gather<<<gA, b, 0, stream>>>(rowptr, ebyrow, m_t, phiv, cd4, deg_inv, coord, h);
    }
    k_final<<<gN, b, 0, stream>>>(h, coord, f2w1, f2b1, f2w2, f2b2, out);
}

// Round 10
// 412.048 us; speedup vs baseline: 1.6796x; 1.6796x over previous
//
#include <hip/hip_runtime.h>
#include <hip/hip_bf16.h>

#define NN 10000
#define NE 100000

typedef __bf16 bf16x8 __attribute__((ext_vector_type(8)));
typedef float  f32x4  __attribute__((ext_vector_type(4)));

__device__ __forceinline__ f32x4 relu4(f32x4 a) {
    a.x = fmaxf(a.x, 0.f); a.y = fmaxf(a.y, 0.f);
    a.z = fmaxf(a.z, 0.f); a.w = fmaxf(a.w, 0.f);
    return a;
}

// ---------------- one-time kernels ----------------

__global__ void k_deg(const int* __restrict__ eidx, int* __restrict__ deg) {
    int e = blockIdx.x * blockDim.x + threadIdx.x;
    if (e < NE) atomicAdd(&deg[eidx[e]], 1);
}

__global__ void k_scan(const int* __restrict__ deg, int* __restrict__ rowptr,
                       int* __restrict__ cursor) {
    __shared__ int ssum[256];
    const int tid = threadIdx.x;
    const int CH = 40;
    const int base = tid * CH;
    int s = 0;
    for (int i = 0; i < CH; ++i) { int n = base + i; if (n < NN) s += deg[n]; }
    ssum[tid] = s;
    __syncthreads();
    for (int off = 1; off < 256; off <<= 1) {
        int t = (tid >= off) ? ssum[tid - off] : 0;
        __syncthreads();
        ssum[tid] += t;
        __syncthreads();
    }
    int run = ssum[tid] - s;
    for (int i = 0; i < CH; ++i) {
        int n = base + i;
        if (n < NN) { rowptr[n] = run; cursor[n] = run; run += deg[n]; }
    }
    if (tid == 255) rowptr[NN] = ssum[255];
}

__global__ void k_fill(const int* __restrict__ eidx, int* __restrict__ cursor,
                       int* __restrict__ ebyrow) {
    int e = blockIdx.x * blockDim.x + threadIdx.x;
    if (e < NE) {
        int r = eidx[e];
        int slot = atomicAdd(&cursor[r], 1);
        ebyrow[slot] = e;
    }
}

__global__ void k_init(const float* __restrict__ x, const float* __restrict__ fc1w,
                       const float* __restrict__ fc1b, const float* __restrict__ cinit,
                       const int* __restrict__ deg,
                       float* __restrict__ h, float* __restrict__ coord,
                       float* __restrict__ deg_inv) {
    int n = blockIdx.x * blockDim.x + threadIdx.x;
    if (n >= NN) return;
    float x0 = x[n*3+0], x1 = x[n*3+1], x2 = x[n*3+2];
    #pragma unroll
    for (int j = 0; j < 32; j += 4) {
        f32x4 a = *(const f32x4*)(fc1b + j);
        a += x0 * (*(const f32x4*)(fc1w + 0*32 + j));
        a += x1 * (*(const f32x4*)(fc1w + 1*32 + j));
        a += x2 * (*(const f32x4*)(fc1w + 2*32 + j));
        *(f32x4*)(h + n*32 + j) = a;   // no relu on fc1 (matches reference)
    }
    coord[n*3+0] = cinit[n*3+0];
    coord[n*3+1] = cinit[n*3+1];
    coord[n*3+2] = cinit[n*3+2];
    int d = deg[n];
    deg_inv[n] = 1.0f / (float)(d > 1 ? d : 1);
}

// Swizzle ker_w3 [128,1024] and ker_w2 [64,128] fp32 -> bf16 MFMA-B fragment order.
__global__ void k_wsw(const float* __restrict__ w3, __bf16* __restrict__ w3sw,
                      const float* __restrict__ w2, __bf16* __restrict__ w2sw) {
    int t = blockIdx.x * blockDim.x + threadIdx.x;
    if (t < 131072) {
        int jj = t & 7;
        int L  = (t >> 3) & 63;
        int ks = (t >> 9) & 3;
        int jt = (t >> 11) & 1;
        int i  = t >> 12;
        int c    = ks*32 + (L >> 4)*8 + jj;              // K index 0..127
        int colv = i*32 + jt*16 + (L & 15);              // output col 0..1023
        w3sw[t] = (__bf16)w3[c*1024 + colv];
    } else if (t < 131072 + 8192) {
        int u = t - 131072;
        int jj = u & 7;
        int L  = (u >> 3) & 63;
        int ks = (u >> 9) & 1;
        int nt = u >> 10;
        int c1 = ks*32 + (L >> 4)*8 + jj;
        int c2 = nt*16 + (L & 15);
        w2sw[u] = (__bf16)w2[c1*128 + c2];
    }
}

// ---------------- per-layer kernels ----------------

// Fused edge MLP. Output kbf is stored in MFMA-A-FRAGMENT-MAJOR order:
//   kbf[(((eb*4 + mt)*4 + ks)*64 + lane)*8 + j] = K[eb*64 + mt*16 + (lane&15)][ks*32 + (lane>>4)*8 + j]
// so both the stores here and k_gemm's A-frag loads are lane-consecutive b128.
// (round-7 layout cost 128 scattered 2B global stores per lane.)
// All LDS tiles are wave-private -> NO __syncthreads anywhere.
__global__ __launch_bounds__(256, 2)
void k_edge12(const float* __restrict__ coord, const int* __restrict__ eidx,
              const float* __restrict__ eattr,
              const float* __restrict__ w1, const float* __restrict__ b1,
              const __bf16* __restrict__ w2sw, const float* __restrict__ b2,
              float* __restrict__ cd4, __bf16* __restrict__ kbf) {
    __shared__ __bf16 ktile[4][64 * 72];    // 9.2 KB/wave; stride 72 (144B rows, 16B-aligned)
    const int tid = threadIdx.x;
    const int wave = tid >> 6, lane = tid & 63;
    const int q = lane >> 4, t = lane & 15;
    const int e = blockIdx.x * 256 + tid;
    const int ec = e < NE ? e : NE - 1;
    const int eb = blockIdx.x * 4 + wave;   // 64-edge block id
    __bf16* kt = ktile[wave];

    // ---- layer 1: this lane's edge, all 64 channels in registers ----
    int r = eidx[ec], c = eidx[NE + ec];
    float dx = coord[r*3+0] - coord[c*3+0];
    float dy = coord[r*3+1] - coord[c*3+1];
    float dz = coord[r*3+2] - coord[c*3+2];
    float rad = dx*dx + dy*dy + dz*dz;
    if (e < NE) {
        f32x4 cdv = {dx, dy, dz, rad};
        *(f32x4*)(cd4 + (size_t)e*4) = cdv;
    }
    float kin[7];
    #pragma unroll
    for (int a = 0; a < 6; ++a) kin[a] = eattr[(size_t)ec*6 + a];
    kin[6] = rad;

    f32x4 acc1[16];
    #pragma unroll
    for (int g = 0; g < 16; ++g) acc1[g] = *(const f32x4*)(b1 + g*4);
    #pragma unroll
    for (int t7 = 0; t7 < 7; ++t7) {
        float kv = kin[t7];
        #pragma unroll
        for (int g = 0; g < 16; ++g)
            acc1[g] += kv * (*(const f32x4*)(w1 + t7*64 + g*4));
    }
    // relu -> bf16 -> XOR-swizzled LDS write (8 chunks of 8 bf16)
    #pragma unroll
    for (int cc = 0; cc < 8; ++cc) {
        f32x4 a0 = relu4(acc1[cc*2]), a1 = relu4(acc1[cc*2+1]);
        bf16x8 pk = {(__bf16)a0.x, (__bf16)a0.y, (__bf16)a0.z, (__bf16)a0.w,
                     (__bf16)a1.x, (__bf16)a1.y, (__bf16)a1.z, (__bf16)a1.w};
        *(bf16x8*)(kt + lane*72 + ((cc ^ (lane & 7)) * 8)) = pk;
    }

    // ---- read layer-1 A-frags (same-wave LDS ordering; no barrier) ----
    bf16x8 af[4][2];
    #pragma unroll
    for (int mt = 0; mt < 4; ++mt) {
        int ep = mt*16 + t;
        #pragma unroll
        for (int ks = 0; ks < 2; ++ks)
            af[mt][ks] = *(const bf16x8*)(kt + ep*72 + (((ks*4 + q) ^ (ep & 7)) * 8));
    }

    // ---- layer 2 MFMA + transpose-through-LDS, in two 64-channel halves ----
    #pragma unroll
    for (int hf2 = 0; hf2 < 2; ++hf2) {
        #pragma unroll
        for (int nn = 0; nn < 4; ++nn) {
            int nt = hf2*4 + nn;
            f32x4 a2[4];
            #pragma unroll
            for (int mt = 0; mt < 4; ++mt) a2[mt] = (f32x4){0.f, 0.f, 0.f, 0.f};
            #pragma unroll
            for (int ks = 0; ks < 2; ++ks) {
                bf16x8 bf_ = *(const bf16x8*)(w2sw + ((nt*2 + ks)*64 + lane) * 8);
                #pragma unroll
                for (int mt = 0; mt < 4; ++mt)
                    a2[mt] = __builtin_amdgcn_mfma_f32_16x16x32_bf16(af[mt][ks], bf_, a2[mt], 0, 0, 0);
            }
            float bias = b2[nt*16 + t];
            #pragma unroll
            for (int mt = 0; mt < 4; ++mt) {
                #pragma unroll
                for (int rr = 0; rr < 4; ++rr)
                    kt[(mt*16 + q*4 + rr)*72 + nn*16 + t] =
                        (__bf16)fmaxf(a2[mt][rr] + bias, 0.f);
            }
        }
        // coalesced fragment-major global stores for this half's 2 k-steps
        #pragma unroll
        for (int mt = 0; mt < 4; ++mt) {
            #pragma unroll
            for (int s = 0; s < 2; ++s) {
                bf16x8 v = *(const bf16x8*)(kt + (mt*16 + t)*72 + s*32 + q*8);
                int ks = hf2*2 + s;
                *(bf16x8*)(kbf + ((((size_t)eb*4 + mt)*4 + ks)*64 + lane) * 8) = v;
            }
        }
    }
}

// Fused big GEMM + einsum epilogue + phi. 4 waves per block, SAME 64 edges;
// each wave owns 8 of the 32 output blocks with a PRIVATE LDS tile (no
// per-iteration barrier). B-frags for i+1 prefetched into registers.
// A-frags load lane-consecutive from fragment-major kbf.
__global__ __launch_bounds__(256, 2)
void k_gemm(const __bf16* __restrict__ kbf, const __bf16* __restrict__ w3sw,
            const float* __restrict__ b3, const float* __restrict__ h,
            const int* __restrict__ eidx,
            const float* __restrict__ cm_w1, const float* __restrict__ cm_b1,
            const float* __restrict__ cm_w2,
            float* __restrict__ m_t, float* __restrict__ phiv) {
    __shared__ float smem[4 * 64 * 36];
    const int lane = threadIdx.x & 63;
    const int wave = threadIdx.x >> 6;
    const int q = lane >> 4, t = lane & 15;
    const int base = blockIdx.x * 64;
    float* wkw = smem + wave * (64 * 36);

    int eg = base + lane;
    int egc = eg < NE ? eg : NE - 1;
    int col = eidx[NE + egc];
    float hcol[32];
    const f32x4* hp = (const f32x4*)(h + (size_t)col * 32);
    #pragma unroll
    for (int v = 0; v < 8; ++v) {
        f32x4 hv = hp[v];
        hcol[v*4+0] = hv.x; hcol[v*4+1] = hv.y; hcol[v*4+2] = hv.z; hcol[v*4+3] = hv.w;
    }

    // A fragments: lane-consecutive b128 from fragment-major kbf
    bf16x8 afrag[4][4];
    #pragma unroll
    for (int mt = 0; mt < 4; ++mt)
        #pragma unroll
        for (int ks = 0; ks < 4; ++ks)
            afrag[mt][ks] = *(const bf16x8*)(
                kbf + ((((size_t)blockIdx.x*4 + mt)*4 + ks)*64 + lane) * 8);

    const float* wkrow = wkw + lane * 36;
    float mv[8];

    bf16x8 bcur[8];
    {
        const __bf16* wb0 = w3sw + (size_t)(wave * 8) * 4096;
        #pragma unroll
        for (int f = 0; f < 8; ++f)
            bcur[f] = *(const bf16x8*)(wb0 + (f*64 + lane) * 8);
    }

    #pragma unroll
    for (int ii = 0; ii < 8; ++ii) {
        const int i = wave * 8 + ii;
        f32x4 acc[4][2];
        #pragma unroll
        for (int mt = 0; mt < 4; ++mt) {
            acc[mt][0] = (f32x4){0.f, 0.f, 0.f, 0.f};
            acc[mt][1] = (f32x4){0.f, 0.f, 0.f, 0.f};
        }
        #pragma unroll
        for (int jt = 0; jt < 2; ++jt) {
            #pragma unroll
            for (int ks = 0; ks < 4; ++ks) {
                bf16x8 bfrag = bcur[jt*4 + ks];
                #pragma unroll
                for (int mt = 0; mt < 4; ++mt)
                    acc[mt][jt] = __builtin_amdgcn_mfma_f32_16x16x32_bf16(
                        afrag[mt][ks], bfrag, acc[mt][jt], 0, 0, 0);
            }
        }
        if (ii < 7) {
            const __bf16* wbn = w3sw + (size_t)(i + 1) * 4096;
            #pragma unroll
            for (int f = 0; f < 8; ++f)
                bcur[f] = *(const bf16x8*)(wbn + (f*64 + lane) * 8);
        }
        float bias0 = b3[i*32 + t];
        float bias1 = b3[i*32 + 16 + t];
        #pragma unroll
        for (int mt = 0; mt < 4; ++mt) {
            #pragma unroll
            for (int r = 0; r < 4; ++r) {
                int row = mt*16 + q*4 + r;
                wkw[row*36 + t]      = acc[mt][0][r] + bias0;
                wkw[row*36 + 16 + t] = acc[mt][1][r] + bias1;
            }
        }
        float s = 0.f;
        #pragma unroll
        for (int v = 0; v < 8; ++v) {
            f32x4 wv = *(const f32x4*)(wkrow + v*4);
            s += wv.x*hcol[v*4+0] + wv.y*hcol[v*4+1] + wv.z*hcol[v*4+2] + wv.w*hcol[v*4+3];
        }
        mv[ii] = s;
    }

    if (eg < NE) {
        f32x4 v0 = {mv[0], mv[1], mv[2], mv[3]};
        f32x4 v1 = {mv[4], mv[5], mv[6], mv[7]};
        *(f32x4*)(m_t + (size_t)eg*32 + wave*8)     = v0;
        *(f32x4*)(m_t + (size_t)eg*32 + wave*8 + 4) = v1;
    }

    __syncthreads();
    float* mvx = smem;                     // 32*65 floats, stride 65
    #pragma unroll
    for (int ii = 0; ii < 8; ++ii)
        mvx[(wave*8 + ii)*65 + lane] = mv[ii];
    __syncthreads();
    if (wave == 0) {
        float m2[32];
        #pragma unroll
        for (int i = 0; i < 32; ++i) m2[i] = mvx[i*65 + lane];
        float phi = 0.f;
        for (int o = 0; o < 32; o += 4) {
            f32x4 a = *(const f32x4*)(cm_b1 + o);
            #pragma unroll
            for (int i = 0; i < 32; ++i)
                a += m2[i] * (*(const f32x4*)(cm_w1 + i*32 + o));
            a = relu4(a);
            f32x4 w2 = *(const f32x4*)(cm_w2 + o);
            phi += a.x*w2.x + a.y*w2.y + a.z*w2.z + a.w*w2.w;
        }
        if (eg < NE) phiv[eg] = phi;
    }
}

// CSR gather: 8 threads per node.
__global__ __launch_bounds__(256, 4)
void k_gather(const int* __restrict__ rowptr, const int* __restrict__ ebyrow,
              const float* __restrict__ m_t, const float* __restrict__ phiv,
              const float* __restrict__ cd4, const float* __restrict__ deg_inv,
              float* __restrict__ coord, float* __restrict__ h) {
    int tid = blockIdx.x * blockDim.x + threadIdx.x;
    int n = tid >> 3, sub = tid & 7;
    if (n >= NN) return;
    int st = rowptr[n], en = rowptr[n+1];
    f32x4 am = {0.f, 0.f, 0.f, 0.f};
    float cx = 0.f, cy = 0.f, cz = 0.f;
    for (int p = st; p < en; ++p) {
        int e = ebyrow[p];
        am += *(const f32x4*)(m_t + (size_t)e*32 + sub*4);
        if (sub == 0) {
            f32x4 cd = *(const f32x4*)(cd4 + (size_t)e*4);
            float ph = phiv[e];
            cx += cd.x * ph; cy += cd.y * ph; cz += cd.z * ph;
        }
    }
    float di = deg_inv[n];
    f32x4 hv = *(const f32x4*)(h + (size_t)n*32 + sub*4);
    hv = relu4(hv + am * di);
    *(f32x4*)(h + (size_t)n*32 + sub*4) = hv;
    if (sub == 0) {
        coord[n*3+0] += cx * di;
        coord[n*3+1] += cy * di;
        coord[n*3+2] += cz * di;
    }
}

__global__ __launch_bounds__(256, 4)
void k_final(const float* __restrict__ h, const float* __restrict__ coord,
             const float* __restrict__ fw1, const float* __restrict__ fb1,
             const float* __restrict__ fw2, const float* __restrict__ fb2,
             float* __restrict__ out) {
    int n = blockIdx.x * blockDim.x + threadIdx.x;
    if (n >= NN) return;
    float hreg[32];
    #pragma unroll
    for (int i = 0; i < 32; ++i) hreg[i] = h[n*32 + i];
    float ov = fb2[0];
    for (int o = 0; o < 64; o += 4) {
        f32x4 a = *(const f32x4*)(fb1 + o);
        #pragma unroll
        for (int i = 0; i < 32; ++i)
            a += hreg[i] * (*(const f32x4*)(fw1 + i*64 + o));
        a = relu4(a);
        f32x4 w2 = *(const f32x4*)(fw2 + o);
        ov += a.x*w2.x + a.y*w2.y + a.z*w2.z + a.w*w2.w;
    }
    out[n] = ov;
    out[NN + n*3 + 0] = coord[n*3+0];
    out[NN + n*3 + 1] = coord[n*3+1];
    out[NN + n*3 + 2] = coord[n*3+2];
}

// ---------------- launch ----------------

extern "C" void kernel_launch(void* const* d_in, const int* in_sizes, int n_in,
                              void* d_out, int out_size, void* d_ws, size_t ws_size,
                              hipStream_t stream) {
    const float* x      = (const float*)d_in[0];
    const int*   eidx   = (const int*)  d_in[1];
    const float* eattr  = (const float*)d_in[2];
    const float* cinit  = (const float*)d_in[3];
    const float* fc1w   = (const float*)d_in[4];
    const float* fc1b   = (const float*)d_in[5];
    const float* kw1    = (const float*)d_in[6];
    const float* kb1    = (const float*)d_in[7];
    const float* kw2    = (const float*)d_in[8];
    const float* kb2    = (const float*)d_in[9];
    const float* kw3    = (const float*)d_in[10];
    const float* kb3    = (const float*)d_in[11];
    const float* cmw1   = (const float*)d_in[12];
    const float* cmb1   = (const float*)d_in[13];
    const float* cmw2   = (const float*)d_in[14];
    const float* f2w1   = (const float*)d_in[15];
    const float* f2b1   = (const float*)d_in[16];
    const float* f2w2   = (const float*)d_in[17];
    const float* f2b2   = (const float*)d_in[18];
    float* out = (float*)d_out;

    char* p = (char*)d_ws;
    auto carve = [&](size_t bytes) {
        void* r = (void*)p;
        p += (bytes + 255) & ~(size_t)255;
        return r;
    };
    const int NEB = ((NE + 255) / 256) * 4;          // 64-edge blocks incl. pad (1564)
    float*  h        = (float*) carve((size_t)NN * 32 * 4);
    float*  coord    = (float*) carve((size_t)NN * 3 * 4);
    int*    deg      = (int*)   carve((size_t)NN * 4);
    float*  deg_inv  = (float*) carve((size_t)NN * 4);
    int*    rowptr   = (int*)   carve((size_t)(NN + 1) * 4);
    int*    cursor   = (int*)   carve((size_t)NN * 4);
    int*    ebyrow   = (int*)   carve((size_t)NE * 4);
    float*  cd4      = (float*) carve((size_t)NE * 4 * 4);
    float*  m_t      = (float*) carve((size_t)NE * 32 * 4);
    float*  phiv     = (float*) carve((size_t)NE * 4);
    __bf16* kbf      = (__bf16*)carve((size_t)NEB * 8192 * 2);   // fragment-major
    __bf16* w3sw     = (__bf16*)carve((size_t)131072 * 2);
    __bf16* w2sw     = (__bf16*)carve((size_t)8192 * 2);

    const int TB = 256;
    dim3 gE((NE + TB - 1) / TB), gN((NN + TB - 1) / TB), b(TB);
    dim3 gG((NE + 63) / 64);                 // 64 edges per block (k_gemm, 256 thr)
    dim3 gA((NN*8 + TB - 1) / TB);

    hipMemsetAsync(deg, 0, (size_t)NN * 4, stream);
    k_deg <<<gE, b, 0, stream>>>(eidx, deg);
    k_scan<<<1, b, 0, stream>>>(deg, rowptr, cursor);
    k_fill<<<gE, b, 0, stream>>>(eidx, cursor, ebyrow);
    k_init<<<gN, b, 0, stream>>>(x, fc1w, fc1b, cinit, deg, h, coord, deg_inv);
    k_wsw <<<544, b, 0, stream>>>(kw3, w3sw, kw2, w2sw);

    for (int d = 0; d < 3; ++d) {
        k_edge12<<<gE, b, 0, stream>>>(coord, eidx, eattr, kw1, kb1, w2sw, kb2, cd4, kbf);
        k_gemm  <<<gG, b, 0, stream>>>(
            kbf, w3sw, kb3, h, eidx, cmw1, cmb1, cmw2, m_t, phiv);
        k_gather<<<gA, b, 0, stream>>>(rowptr, ebyrow, m_t, phiv, cd4, deg_inv, coord, h);
    }
    k_final<<<gN, b, 0, stream>>>(h, coord, f2w1, f2b1, f2w2, f2b2, out);
}